// Round 8
// baseline (473.141 us; speedup 1.0000x reference)
//
#include <hip/hip_runtime.h>
#include <hip/hip_bf16.h>
#include <stdint.h>

// Problem constants
#define NROWS 4096
#define NCLS  97
#define EMB   768
#define KTOT  49152                 // EMB * 64
#define OUT_ELEMS (NROWS * NCLS)    // 397312
#define W_ELEMS  (NCLS * KTOT)      // 4,767,744

typedef __attribute__((ext_vector_type(8)))  short short8;
typedef __attribute__((ext_vector_type(4)))  float floatx4;
typedef __bf16 bf16x2 __attribute__((ext_vector_type(2)));
typedef __bf16 bf16x8 __attribute__((ext_vector_type(8)));

__device__ __forceinline__ uint32_t pkmul(uint32_t a, uint32_t b) {
  bf16x2 x = __builtin_bit_cast(bf16x2, a);
  bf16x2 y = __builtin_bit_cast(bf16x2, b);
  bf16x2 r = x * y;
  return __builtin_bit_cast(uint32_t, r);
}

__device__ __forceinline__ uint4 cvt8(float4 a, float4 b) {
  bf16x8 v;
  v[0] = (__bf16)a.x; v[1] = (__bf16)a.y; v[2] = (__bf16)a.z; v[3] = (__bf16)a.w;
  v[4] = (__bf16)b.x; v[5] = (__bf16)b.y; v[6] = (__bf16)b.z; v[7] = (__bf16)b.w;
  return __builtin_bit_cast(uint4, v);
}

// One-time W f32 -> bf16 mirror: 8 elems/thread.
__global__ void cvt_w(const float* __restrict__ src, uint4* __restrict__ dst, int n8)
{
  int i = blockIdx.x * blockDim.x + threadIdx.x;
  if (i >= n8) return;
  const float4* p = (const float4*)src + (size_t)i * 2;
  dst[i] = cvt8(p[0], p[1]);
}

// Fused on-the-fly-A GEMM: logits[n,c] = sum_k A[n,k]*W[c,k],
// A[n, kb*4096 + i*64 + j] = b1[n,kb,i] * b2[n,kb,j] (registers).
// R8: double-buffered LDS (ONE barrier per 64-kappa window), W staged from a
// bf16 mirror (WB16=true) or f32 direct (fallback), KS=24 split-K for 3
// blocks/CU occupancy.
// MFMA 16x16x32 bf16, verified triple:
//   A: lane l holds A[m=l&15][k=(l>>4)*8+j]; B: W[c=l&15][k=(l>>4)*8+j]
//   D: lane l, reg r: col(c)=l&15, row(n)=(l>>4)*4+r
template<bool WB16>
__global__ __launch_bounds__(256, 3)
void bilinear_main(const float* __restrict__ b1g,
                   const float* __restrict__ b2g,
                   const void* __restrict__ Wg,
                   const float* __restrict__ biasg,
                   float* __restrict__ P,
                   float* __restrict__ outd,
                   int klen)
{
  __shared__ uint4 smem[2][1152];   // 2 x (128 rows x (8+1 pad) chunks) = 36 KB
  const int tid  = threadIdx.x;
  const int w    = tid >> 6;
  const int l    = tid & 63;
  const int l15  = l & 15;
  const int quad = l >> 4;
  const int mhalf = w & 1;
  const int chalf = w >> 1;
  const int bm = blockIdx.x;
  const int k0 = blockIdx.y * klen;

  // Staging descriptors: 1024 chunks of 8 elems; chunk s: row c=s>>3, slot g=s&7.
  const char* wsrcB[4];
  int sidx[4];
#pragma unroll
  for (int r = 0; r < 4; ++r) {
    int s  = r * 256 + tid;
    int c  = s >> 3;
    int g  = s & 7;
    int cc = c > 96 ? 96 : c;
    wsrcB[r] = (const char*)Wg + (WB16 ? ((size_t)cc * KTOT * 2 + g * 16)
                                       : ((size_t)cc * KTOT * 4 + g * 32));
    sidx[r]  = c * 9 + g;
  }

  int nrow[4];
#pragma unroll
  for (int rt = 0; rt < 4; ++rt) nrow[rt] = bm * 128 + mhalf * 64 + rt * 16 + l15;
  int ccol[4];
#pragma unroll
  for (int ct = 0; ct < 4; ++ct) ccol[ct] = chalf * 64 + ct * 16 + l15;
  int rbase[4];
#pragma unroll
  for (int ct = 0; ct < 4; ++ct) rbase[ct] = ccol[ct] * 9;

  floatx4 acc[4][4];
#pragma unroll
  for (int rt = 0; rt < 4; ++rt)
#pragma unroll
    for (int ct = 0; ct < 4; ++ct)
      acc[rt][ct] = floatx4{0.f, 0.f, 0.f, 0.f};

  uint4  b2c[4][2];
  float4 b1f[4][2];
  int cur_k = -1;
  const int nwin = klen >> 6;

  // Prologue: stage window 0 into buffer 0.
  uint4 stg[4];
#pragma unroll
  for (int r = 0; r < 4; ++r) {
    if (WB16) {
      stg[r] = *(const uint4*)(wsrcB[r] + (size_t)k0 * 2);
    } else {
      const float4* p = (const float4*)(wsrcB[r] + (size_t)k0 * 4);
      stg[r] = cvt8(p[0], p[1]);
    }
  }
#pragma unroll
  for (int r = 0; r < 4; ++r) smem[0][sidx[r]] = stg[r];
  __syncthreads();

  for (int gwin = 0; gwin < nwin; gwin += 8) {
    const int kap0 = k0 + (gwin << 6);
    const int kblk = kap0 >> 12;
    const int i0   = (kap0 >> 6) & 63;
    if (kblk != cur_k) {
      cur_k = kblk;
#pragma unroll
      for (int rt = 0; rt < 4; ++rt)
#pragma unroll
        for (int kh = 0; kh < 2; ++kh) {
          const float* p = b2g + (size_t)nrow[rt] * EMB + kblk * 64 + kh * 32 + quad * 8;
          b2c[rt][kh] = cvt8(((const float4*)p)[0], ((const float4*)p)[1]);
        }
    }
#pragma unroll
    for (int rt = 0; rt < 4; ++rt) {
      const float* p = b1g + (size_t)nrow[rt] * EMB + kblk * 64 + i0;
      b1f[rt][0] = ((const float4*)p)[0];
      b1f[rt][1] = ((const float4*)p)[1];
    }

#pragma unroll
    for (int ii = 0; ii < 8; ++ii) {
      const int wdx  = gwin + ii;
      const bool more = (wdx + 1) < nwin;

      // Prefetch next window's W chunk (lands during this window's MFMAs).
      if (more) {
        const size_t kb = (size_t)(k0 + ((wdx + 1) << 6));
#pragma unroll
        for (int r = 0; r < 4; ++r) {
          if (WB16) {
            stg[r] = *(const uint4*)(wsrcB[r] + kb * 2);
          } else {
            const float4* p = (const float4*)(wsrcB[r] + kb * 4);
            stg[r] = cvt8(p[0], p[1]);
          }
        }
      }

      // A fragments for window wdx: elem j = bf16(b1[n,i0+ii]) * b2c[...j]
      uint4 afr[4][2];
#pragma unroll
      for (int rt = 0; rt < 4; ++rt) {
        float bs = ((const float*)&b1f[rt][ii >> 2])[ii & 3];
        __bf16 hb = (__bf16)bs;
        uint32_t hx = (uint32_t)__builtin_bit_cast(uint16_t, hb);
        uint32_t s2 = hx | (hx << 16);
#pragma unroll
        for (int kh = 0; kh < 2; ++kh) {
          afr[rt][kh].x = pkmul(s2, b2c[rt][kh].x);
          afr[rt][kh].y = pkmul(s2, b2c[rt][kh].y);
          afr[rt][kh].z = pkmul(s2, b2c[rt][kh].z);
          afr[rt][kh].w = pkmul(s2, b2c[rt][kh].w);
        }
      }

      // MFMAs read current buffer.
      const uint4* sb = smem[wdx & 1];
#pragma unroll
      for (int kh = 0; kh < 2; ++kh) {
        short8 wf[4];
#pragma unroll
        for (int ct = 0; ct < 4; ++ct)
          wf[ct] = __builtin_bit_cast(short8, sb[rbase[ct] + kh * 4 + quad]);
#pragma unroll
        for (int rt = 0; rt < 4; ++rt) {
          short8 af = __builtin_bit_cast(short8, afr[rt][kh]);
#pragma unroll
          for (int ct = 0; ct < 4; ++ct)
            acc[rt][ct] = __builtin_amdgcn_mfma_f32_16x16x32_bf16(
                              af, wf[ct], acc[rt][ct], 0, 0, 0);
        }
      }

      // Write next window into alternate buffer; one barrier per window.
      if (more) {
        uint4* sw = smem[(wdx + 1) & 1];
#pragma unroll
        for (int r = 0; r < 4; ++r) sw[sidx[r]] = stg[r];
      }
      __syncthreads();
    }
  }

  // Epilogue. D: col(c)=l15, row(n)=quad*4+r within each 16x16 tile.
  if (P) {
    float* Pb = P + (size_t)blockIdx.y * OUT_ELEMS;
#pragma unroll
    for (int rt = 0; rt < 4; ++rt)
#pragma unroll
      for (int ct = 0; ct < 4; ++ct) {
        const int c = ccol[ct];
        if (c < NCLS) {
#pragma unroll
          for (int r = 0; r < 4; ++r) {
            const int row = bm * 128 + mhalf * 64 + rt * 16 + quad * 4 + r;
            Pb[(size_t)row * NCLS + c] = acc[rt][ct][r];
          }
        }
      }
  } else {
#pragma unroll
    for (int rt = 0; rt < 4; ++rt)
#pragma unroll
      for (int ct = 0; ct < 4; ++ct) {
        const int c = ccol[ct];
        if (c < NCLS) {
          const float bv = biasg[c];
#pragma unroll
          for (int r = 0; r < 4; ++r) {
            const int row = bm * 128 + mhalf * 64 + rt * 16 + quad * 4 + r;
            outd[(size_t)row * NCLS + c] = acc[rt][ct][r] + bv;
          }
        }
      }
  }
}

// Sum KS partial slices + f32 bias -> f32 output. float4-vectorized.
__global__ void reduce_bias(const float* __restrict__ P,
                            const float* __restrict__ biasg,
                            float* __restrict__ out, int KS)
{
  int i = blockIdx.x * blockDim.x + threadIdx.x;
  const int n4 = OUT_ELEMS / 4;           // 99328
  if (i >= n4) return;
  int c0 = (i * 4) % NCLS;
  int c1 = c0 + 1 == NCLS ? 0 : c0 + 1;
  int c2 = c1 + 1 == NCLS ? 0 : c1 + 1;
  int c3 = c2 + 1 == NCLS ? 0 : c2 + 1;
  float4 s;
  s.x = biasg[c0]; s.y = biasg[c1]; s.z = biasg[c2]; s.w = biasg[c3];
  const float4* P4 = (const float4*)P;
  for (int t = 0; t < KS; ++t) {
    float4 v = P4[(size_t)t * n4 + i];
    s.x += v.x; s.y += v.y; s.z += v.z; s.w += v.w;
  }
  ((float4*)out)[i] = s;
}

extern "C" void kernel_launch(void* const* d_in, const int* in_sizes, int n_in,
                              void* d_out, int out_size, void* d_ws, size_t ws_size,
                              hipStream_t stream) {
  const float* b1f = (const float*)d_in[0];   // [4096,768] f32
  const float* b2f = (const float*)d_in[1];   // [4096,768] f32
  const float* Wf  = (const float*)d_in[2];   // [97, 49152] f32
  const float* bbf = (const float*)d_in[3];   // [97] f32
  float* out = (float*)d_out;

  const size_t wb    = (size_t)W_ELEMS * 2;        // 9,535,488 (16B-aligned)
  const size_t slice = (size_t)OUT_ELEMS * 4;      // 1,589,248
  static const int cands[] = {24, 16, 12, 8, 6, 4, 3, 2, 1};  // klen mult of 512

  int KS = 0; bool mir = false;
  for (int i = 0; i < 9; ++i)
    if (wb + (size_t)cands[i] * slice <= ws_size) { KS = cands[i]; mir = true; break; }
  if (!mir)
    for (int i = 0; i < 9; ++i)
      if ((size_t)cands[i] * slice <= ws_size) { KS = cands[i]; break; }

  if (mir) {
    uint4* Wb = (uint4*)d_ws;
    float* P  = (float*)((char*)d_ws + wb);
    cvt_w<<<(W_ELEMS / 8 + 255) / 256, 256, 0, stream>>>(Wf, Wb, W_ELEMS / 8);
    bilinear_main<true><<<dim3(32, KS), 256, 0, stream>>>(
        b1f, b2f, (const void*)Wb, bbf, P, nullptr, KTOT / KS);
    reduce_bias<<<(OUT_ELEMS / 4 + 255) / 256, 256, 0, stream>>>(P, bbf, out, KS);
  } else if (KS > 0) {
    float* P = (float*)d_ws;
    bilinear_main<false><<<dim3(32, KS), 256, 0, stream>>>(
        b1f, b2f, (const void*)Wf, bbf, P, nullptr, KTOT / KS);
    reduce_bias<<<(OUT_ELEMS / 4 + 255) / 256, 256, 0, stream>>>(P, bbf, out, KS);
  } else {
    bilinear_main<false><<<dim3(32, 1), 256, 0, stream>>>(
        b1f, b2f, (const void*)Wf, bbf, nullptr, out, KTOT);
  }
}

// Round 9
// 330.016 us; speedup vs baseline: 1.4337x; 1.4337x over previous
//
#include <hip/hip_runtime.h>
#include <hip/hip_bf16.h>
#include <stdint.h>

// Problem constants
#define NROWS 4096
#define NCLS  97
#define EMB   768
#define KTOT  49152                 // EMB * 64
#define OUT_ELEMS (NROWS * NCLS)    // 397312
#define W_ELEMS  (NCLS * KTOT)      // 4,767,744
#define E_ELEMS  (NROWS * EMB)      // 3,145,728

typedef __attribute__((ext_vector_type(8)))  short short8;
typedef __attribute__((ext_vector_type(4)))  float floatx4;
typedef __bf16 bf16x2 __attribute__((ext_vector_type(2)));
typedef __bf16 bf16x8 __attribute__((ext_vector_type(8)));

__device__ __forceinline__ uint32_t pkmul(uint32_t a, uint32_t b) {
  bf16x2 x = __builtin_bit_cast(bf16x2, a);
  bf16x2 y = __builtin_bit_cast(bf16x2, b);
  bf16x2 r = x * y;
  return __builtin_bit_cast(uint32_t, r);
}

__device__ __forceinline__ uint4 cvt8(float4 a, float4 b) {
  bf16x8 v;
  v[0] = (__bf16)a.x; v[1] = (__bf16)a.y; v[2] = (__bf16)a.z; v[3] = (__bf16)a.w;
  v[4] = (__bf16)b.x; v[5] = (__bf16)b.y; v[6] = (__bf16)b.z; v[7] = (__bf16)b.w;
  return __builtin_bit_cast(uint4, v);
}

// One fused f32->bf16 mirror kernel: dst = [Wb | b1b | b2b] as 8-elem chunks.
__global__ void cvt_all(const float* __restrict__ W,
                        const float* __restrict__ b1,
                        const float* __restrict__ b2,
                        uint4* __restrict__ dst)
{
  const int nW8 = W_ELEMS / 8;   // 595,968
  const int nE8 = E_ELEMS / 8;   // 393,216
  int i = blockIdx.x * blockDim.x + threadIdx.x;
  if (i >= nW8 + 2 * nE8) return;
  const float4* src;
  if (i < nW8)            src = (const float4*)W  + (size_t)2 * i;
  else if (i < nW8 + nE8) src = (const float4*)b1 + (size_t)2 * (i - nW8);
  else                    src = (const float4*)b2 + (size_t)2 * (i - nW8 - nE8);
  dst[i] = cvt8(src[0], src[1]);
}

// Fused on-the-fly-A GEMM: logits[n,c] = sum_k A[n,k]*W[c,k],
// A[n, kb*4096 + i*64 + j] = b1[n,kb,i] * b2[n,kb,j] (registers).
// R9: 64-row WG tiles (grid 64 x KS) + slim 2rt x 4ct wave tile (acc=32 VGPR)
// -> 4 blocks/CU at <=128 VGPRs, launch_bounds(256,4). bf16 mirrors for
// W/b1/b2 (MIR) remove all in-loop cvt chains. Single-buffer LDS, 2 barriers
// per 64-kappa window (proven R7 structure).
// MFMA 16x16x32 bf16, verified triple:
//   A: lane l holds A[m=l&15][k=(l>>4)*8+j]; B: W[c=l&15][k=(l>>4)*8+j]
//   D: lane l, reg r: col(c)=l&15, row(n)=(l>>4)*4+r
template<bool MIR>
__global__ __launch_bounds__(256, 4)
void bilinear_main(const void* __restrict__ b1p,
                   const void* __restrict__ b2p,
                   const void* __restrict__ Wp,
                   const float* __restrict__ biasg,
                   float* __restrict__ P,
                   float* __restrict__ outd,
                   int klen)
{
  __shared__ uint4 smem[1152];   // 128 rows x (8 chunks + 1 pad) = 18 KB
  const int tid  = threadIdx.x;
  const int w    = tid >> 6;
  const int l    = tid & 63;
  const int l15  = l & 15;
  const int quad = l >> 4;
  const int mhalf = w & 1;
  const int chalf = w >> 1;
  const int bm = blockIdx.x;       // 64 row-tiles of 64 rows
  const int k0 = blockIdx.y * klen;

  // Staging: 1024 chunks of 8 elems; chunk s: row c=s>>3, slot g=s&7.
  size_t woff[4];
  int sidx[4];
#pragma unroll
  for (int r = 0; r < 4; ++r) {
    int s  = r * 256 + tid;
    int c  = s >> 3;
    int g  = s & 7;
    int cc = c > 96 ? 96 : c;
    woff[r] = MIR ? ((size_t)cc * (KTOT * 2) + g * 16)
                  : ((size_t)cc * (KTOT * 4) + g * 32);
    sidx[r] = c * 9 + g;
  }

  int nrow[2];
#pragma unroll
  for (int rt = 0; rt < 2; ++rt) nrow[rt] = bm * 64 + mhalf * 32 + rt * 16 + l15;
  int rbase[4];
#pragma unroll
  for (int ct = 0; ct < 4; ++ct) rbase[ct] = (chalf * 64 + ct * 16 + l15) * 9;

  floatx4 acc[2][4];
#pragma unroll
  for (int rt = 0; rt < 2; ++rt)
#pragma unroll
    for (int ct = 0; ct < 4; ++ct)
      acc[rt][ct] = floatx4{0.f, 0.f, 0.f, 0.f};

  uint4 b2c[2][2];   // bf16 b2[nrow[rt], kblk, kh*32+quad*8 .. +7]
  uint4 b1c[2];      // bf16 b1[nrow[rt], kblk, i0 .. i0+7]
  int cur_k = -1;
  const int nwin = klen >> 6;

  for (int gwin = 0; gwin < nwin; gwin += 8) {
    const int kap0 = k0 + (gwin << 6);
    const int kblk = kap0 >> 12;
    const int i0   = (kap0 >> 6) & 63;
    if (kblk != cur_k) {
      cur_k = kblk;
#pragma unroll
      for (int rt = 0; rt < 2; ++rt)
#pragma unroll
        for (int kh = 0; kh < 2; ++kh) {
          if (MIR) {
            b2c[rt][kh] = *(const uint4*)((const char*)b2p +
                            (size_t)nrow[rt] * 1536 + kblk * 128 + kh * 64 + quad * 16);
          } else {
            const float* p = (const float*)b2p + (size_t)nrow[rt] * EMB +
                             kblk * 64 + kh * 32 + quad * 8;
            b2c[rt][kh] = cvt8(((const float4*)p)[0], ((const float4*)p)[1]);
          }
        }
    }
#pragma unroll
    for (int rt = 0; rt < 2; ++rt) {
      if (MIR) {
        b1c[rt] = *(const uint4*)((const char*)b1p +
                     (size_t)nrow[rt] * 1536 + kblk * 128 + i0 * 2);
      } else {
        const float* p = (const float*)b1p + (size_t)nrow[rt] * EMB + kblk * 64 + i0;
        b1c[rt] = cvt8(((const float4*)p)[0], ((const float4*)p)[1]);
      }
    }

#pragma unroll
    for (int ii = 0; ii < 8; ++ii) {
      const int kr = kap0 + (ii << 6);   // this window's kappa base

      // Stage W window (issued early; latency overlaps afr build)
      uint4 stg[4];
#pragma unroll
      for (int r = 0; r < 4; ++r) {
        if (MIR) {
          stg[r] = *(const uint4*)((const char*)Wp + woff[r] + (size_t)kr * 2);
        } else {
          const float4* p = (const float4*)((const char*)Wp + woff[r] + (size_t)kr * 4);
          stg[r] = cvt8(p[0], p[1]);
        }
      }

      // A fragments: afr[rt][kh] elem j = b1bf[n,i0+ii] * b2bf[n, kh*32+quad*8+j]
      uint4 afr[2][2];
#pragma unroll
      for (int rt = 0; rt < 2; ++rt) {
        uint32_t d  = (&b1c[rt].x)[ii >> 1];
        uint32_t h  = (ii & 1) ? (d >> 16) : (d & 0xffffu);
        uint32_t s2 = h | (h << 16);
#pragma unroll
        for (int kh = 0; kh < 2; ++kh) {
          afr[rt][kh].x = pkmul(s2, b2c[rt][kh].x);
          afr[rt][kh].y = pkmul(s2, b2c[rt][kh].y);
          afr[rt][kh].z = pkmul(s2, b2c[rt][kh].z);
          afr[rt][kh].w = pkmul(s2, b2c[rt][kh].w);
        }
      }

      __syncthreads();                 // prior window's LDS reads done
#pragma unroll
      for (int r = 0; r < 4; ++r)
        smem[sidx[r]] = stg[r];        // ds_write_b128
      __syncthreads();                 // tile visible

#pragma unroll
      for (int kh = 0; kh < 2; ++kh) {
        short8 wf[4];
#pragma unroll
        for (int ct = 0; ct < 4; ++ct)
          wf[ct] = __builtin_bit_cast(short8, smem[rbase[ct] + kh * 4 + quad]);
#pragma unroll
        for (int rt = 0; rt < 2; ++rt) {
          short8 af = __builtin_bit_cast(short8, afr[rt][kh]);
#pragma unroll
          for (int ct = 0; ct < 4; ++ct)
            acc[rt][ct] = __builtin_amdgcn_mfma_f32_16x16x32_bf16(
                              af, wf[ct], acc[rt][ct], 0, 0, 0);
        }
      }
    }
  }

  // Epilogue. D: col(c)=l15, row(n)=quad*4+r within each 16x16 tile.
  if (P) {
    float* Pb = P + (size_t)blockIdx.y * OUT_ELEMS;
#pragma unroll
    for (int rt = 0; rt < 2; ++rt)
#pragma unroll
      for (int ct = 0; ct < 4; ++ct) {
        const int c = chalf * 64 + ct * 16 + l15;
        if (c < NCLS) {
#pragma unroll
          for (int r = 0; r < 4; ++r) {
            const int row = bm * 64 + mhalf * 32 + rt * 16 + quad * 4 + r;
            Pb[(size_t)row * NCLS + c] = acc[rt][ct][r];
          }
        }
      }
  } else {
#pragma unroll
    for (int rt = 0; rt < 2; ++rt)
#pragma unroll
      for (int ct = 0; ct < 4; ++ct) {
        const int c = chalf * 64 + ct * 16 + l15;
        if (c < NCLS) {
          const float bv = biasg[c];
#pragma unroll
          for (int r = 0; r < 4; ++r) {
            const int row = bm * 64 + mhalf * 32 + rt * 16 + quad * 4 + r;
            outd[(size_t)row * NCLS + c] = acc[rt][ct][r] + bv;
          }
        }
      }
  }
}

// Sum KS partial slices + f32 bias -> f32 output. float4-vectorized.
__global__ void reduce_bias(const float* __restrict__ P,
                            const float* __restrict__ biasg,
                            float* __restrict__ out, int KS)
{
  int i = blockIdx.x * blockDim.x + threadIdx.x;
  const int n4 = OUT_ELEMS / 4;           // 99328
  if (i >= n4) return;
  int c0 = (i * 4) % NCLS;
  int c1 = c0 + 1 == NCLS ? 0 : c0 + 1;
  int c2 = c1 + 1 == NCLS ? 0 : c1 + 1;
  int c3 = c2 + 1 == NCLS ? 0 : c2 + 1;
  float4 s;
  s.x = biasg[c0]; s.y = biasg[c1]; s.z = biasg[c2]; s.w = biasg[c3];
  const float4* P4 = (const float4*)P;
  for (int t = 0; t < KS; ++t) {
    float4 v = P4[(size_t)t * n4 + i];
    s.x += v.x; s.y += v.y; s.z += v.z; s.w += v.w;
  }
  ((float4*)out)[i] = s;
}

extern "C" void kernel_launch(void* const* d_in, const int* in_sizes, int n_in,
                              void* d_out, int out_size, void* d_ws, size_t ws_size,
                              hipStream_t stream) {
  const float* b1f = (const float*)d_in[0];   // [4096,768] f32
  const float* b2f = (const float*)d_in[1];   // [4096,768] f32
  const float* Wf  = (const float*)d_in[2];   // [97, 49152] f32
  const float* bbf = (const float*)d_in[3];   // [97] f32
  float* out = (float*)d_out;

  const size_t wb      = (size_t)W_ELEMS * 2;      // 9,535,488
  const size_t eb      = (size_t)E_ELEMS * 2;      // 6,291,456
  const size_t reserve = wb + 2 * eb;              // 22,118,400
  const size_t slice   = (size_t)OUT_ELEMS * 4;    // 1,589,248
  static const int cands[] = {16, 12, 8, 6, 4, 3, 2, 1};  // klen mult of 512

  int KS = 0; bool mir = false;
  for (int i = 0; i < 8; ++i)
    if (reserve + (size_t)cands[i] * slice <= ws_size) { KS = cands[i]; mir = true; break; }
  if (!mir)
    for (int i = 0; i < 8; ++i)
      if ((size_t)cands[i] * slice <= ws_size) { KS = cands[i]; break; }

  if (mir) {
    uint4* mirror = (uint4*)d_ws;
    const char* Wb  = (const char*)d_ws;
    const char* b1b = (const char*)d_ws + wb;
    const char* b2b = (const char*)d_ws + wb + eb;
    float* P = (float*)((char*)d_ws + reserve);
    const int nchunks = W_ELEMS / 8 + 2 * (E_ELEMS / 8);   // 1,382,400
    cvt_all<<<(nchunks + 255) / 256, 256, 0, stream>>>(Wf, b1f, b2f, mirror);
    bilinear_main<true><<<dim3(64, KS), 256, 0, stream>>>(
        (const void*)b1b, (const void*)b2b, (const void*)Wb, bbf, P, nullptr, KTOT / KS);
    reduce_bias<<<(OUT_ELEMS / 4 + 255) / 256, 256, 0, stream>>>(P, bbf, out, KS);
  } else if (KS > 0) {
    float* P = (float*)d_ws;
    bilinear_main<false><<<dim3(64, KS), 256, 0, stream>>>(
        (const void*)b1f, (const void*)b2f, (const void*)Wf, bbf, P, nullptr, KTOT / KS);
    reduce_bias<<<(OUT_ELEMS / 4 + 255) / 256, 256, 0, stream>>>(P, bbf, out, KS);
  } else {
    bilinear_main<false><<<dim3(64, 1), 256, 0, stream>>>(
        (const void*)b1f, (const void*)b2f, (const void*)Wf, bbf, nullptr, out, KTOT);
  }
}

// Round 10
// 153.767 us; speedup vs baseline: 3.0770x; 2.1462x over previous
//
#include <hip/hip_runtime.h>
#include <hip/hip_bf16.h>
#include <stdint.h>

// Problem constants
#define NROWS 4096
#define NCLS  97
#define EMB   768
#define KTOT  49152                 // EMB * 64
#define OUT_ELEMS (NROWS * NCLS)    // 397312
#define E_ELEMS  (NROWS * EMB)      // 3,145,728
#define NK32  (KTOT / 32)           // 1536 k-chunks of 32
#define WT_BYTES ((size_t)NK32 * 128 * 64)   // 12,582,912 (Wt: [kc][c<128][32] bf16)
#define EB_BYTES ((size_t)E_ELEMS * 2)       // 6,291,456

typedef __attribute__((ext_vector_type(8)))  short short8;
typedef __attribute__((ext_vector_type(4)))  float floatx4;
typedef __bf16 bf16x2 __attribute__((ext_vector_type(2)));
typedef __bf16 bf16x8 __attribute__((ext_vector_type(8)));

__device__ __forceinline__ uint32_t pkmul(uint32_t a, uint32_t b) {
  bf16x2 x = __builtin_bit_cast(bf16x2, a);
  bf16x2 y = __builtin_bit_cast(bf16x2, b);
  bf16x2 r = x * y;
  return __builtin_bit_cast(uint32_t, r);
}

__device__ __forceinline__ uint4 cvt8(float4 a, float4 b) {
  bf16x8 v;
  v[0] = (__bf16)a.x; v[1] = (__bf16)a.y; v[2] = (__bf16)a.z; v[3] = (__bf16)a.w;
  v[4] = (__bf16)b.x; v[5] = (__bf16)b.y; v[6] = (__bf16)b.z; v[7] = (__bf16)b.w;
  return __builtin_bit_cast(uint4, v);
}

// Prep: build Wt (W transposed into MFMA B-fragment order, bf16, classes
// padded to 128 with zeros) and optional bf16 mirrors of b1/b2.
// Wt 16B-chunk t: eo=t&3 (8-elem octet), c=(t>>2)&127, kc=t>>9:
//   Wt byte addr = kc*8192 + c*64 + eo*16  <-> W[c][kc*32 + eo*8 .. +7]
__global__ void prep(const float* __restrict__ W,
                     const float* __restrict__ b1,
                     const float* __restrict__ b2,
                     uint4* __restrict__ wt,
                     uint4* __restrict__ b1b,
                     uint4* __restrict__ b2b,
                     int nmax)
{
  const int nwt = NK32 * 128 * 4;      // 786,432
  const int nE8 = E_ELEMS / 8;         // 393,216
  int t = blockIdx.x * blockDim.x + threadIdx.x;
  if (t >= nmax) return;
  if (t < nwt) {
    int eo = t & 3;
    int c  = (t >> 2) & 127;
    int kc = t >> 9;
    uint4 v = uint4{0u, 0u, 0u, 0u};
    if (c < NCLS) {
      const float4* p = (const float4*)(W + (size_t)c * KTOT + kc * 32 + eo * 8);
      v = cvt8(p[0], p[1]);
    }
    wt[t] = v;
  } else if (t < nwt + nE8) {
    int i = t - nwt;
    const float4* p = (const float4*)b1 + (size_t)2 * i;
    b1b[i] = cvt8(p[0], p[1]);
  } else {
    int i = t - nwt - nE8;
    const float4* p = (const float4*)b2 + (size_t)2 * i;
    b2b[i] = cvt8(p[0], p[1]);
  }
}

// Fused on-the-fly-A GEMM, R10: NO LDS, NO BARRIERS.
// logits[n,c] = sum_k A[n,k]*W[c,k]; A[n, kb*4096+i*64+j] = b1[n,kb,i]*b2[n,kb,j].
// B fragments come straight from Wt via one coalesced global_load_dwordx4 per
// (kh,ct); A fragments built in registers (pkmul). Straight-line K-loop =
// MFMA/load interleave the compiler pipelines with vmcnt(N).
// MFMA 16x16x32 bf16 verified triple:
//   A: lane l holds A[m=l&15][k=(l>>4)*8+j]; B: W[c=l&15][k=(l>>4)*8+j]
//   D: lane l, reg r: col(c)=l&15, row(n)=(l>>4)*4+r
// Grid (KS, 32): x = k-slice (XCD co-location: linear id % 8 = x % 8 when
// KS%8==0 -> same W slice stays in one XCD's L2), y = 128-row tile.
template<bool BMIR>
__global__ __launch_bounds__(256, 2)
void bilinear_main(const void* __restrict__ b1p,
                   const void* __restrict__ b2p,
                   const char* __restrict__ Wt,
                   const float* __restrict__ biasg,
                   float* __restrict__ P,
                   float* __restrict__ outd,
                   int klen)
{
  const int tid  = threadIdx.x;
  const int w    = tid >> 6;
  const int l    = tid & 63;
  const int l15  = l & 15;
  const int quad = l >> 4;
  const int mhalf = w & 1;
  const int chalf = w >> 1;
  const int bm = blockIdx.y;
  const int k0 = blockIdx.x * klen;

  int nrow[4];
#pragma unroll
  for (int rt = 0; rt < 4; ++rt) nrow[rt] = bm * 128 + mhalf * 64 + rt * 16 + l15;

  // Lane-fixed Wt base for this block's k-range.
  const char* wtl = Wt + (size_t)(k0 >> 5) * 8192
                       + (chalf * 64 + l15) * 64 + quad * 16;

  floatx4 acc[4][4];
#pragma unroll
  for (int rt = 0; rt < 4; ++rt)
#pragma unroll
    for (int ct = 0; ct < 4; ++ct)
      acc[rt][ct] = floatx4{0.f, 0.f, 0.f, 0.f};

  uint4 b2c[4][2];   // bf16 b2[nrow[rt], kblk, kh*32+quad*8 .. +7]
  uint4 b1c[4];      // bf16 b1[nrow[rt], kblk, i0 .. i0+7]
  int cur_k = -1;
  const int nwin = klen >> 6;

  for (int gwin = 0; gwin < nwin; gwin += 8) {
    const int kap0 = k0 + (gwin << 6);
    const int kblk = kap0 >> 12;
    const int i0   = (kap0 >> 6) & 63;
    if (kblk != cur_k) {
      cur_k = kblk;
#pragma unroll
      for (int rt = 0; rt < 4; ++rt)
#pragma unroll
        for (int kh = 0; kh < 2; ++kh) {
          if (BMIR) {
            b2c[rt][kh] = *(const uint4*)((const char*)b2p +
                            (size_t)nrow[rt] * 1536 + kblk * 128 + kh * 64 + quad * 16);
          } else {
            const float* p = (const float*)b2p + (size_t)nrow[rt] * EMB +
                             kblk * 64 + kh * 32 + quad * 8;
            b2c[rt][kh] = cvt8(((const float4*)p)[0], ((const float4*)p)[1]);
          }
        }
    }
#pragma unroll
    for (int rt = 0; rt < 4; ++rt) {
      if (BMIR) {
        b1c[rt] = *(const uint4*)((const char*)b1p +
                     (size_t)nrow[rt] * 1536 + kblk * 128 + i0 * 2);
      } else {
        const float* p = (const float*)b1p + (size_t)nrow[rt] * EMB + kblk * 64 + i0;
        b1c[rt] = cvt8(((const float4*)p)[0], ((const float4*)p)[1]);
      }
    }

#pragma unroll
    for (int ii = 0; ii < 8; ++ii) {
      // This window's Wt pointer: k-chunks (kap0>>5)+ii*2 and +1.
      const char* pw = wtl + (size_t)(gwin + ii) * 16384;

      // b1 scalar for this window, broadcast to a bf16 pair.
      uint32_t s2[4];
#pragma unroll
      for (int rt = 0; rt < 4; ++rt) {
        uint32_t d = (&b1c[rt].x)[ii >> 1];
        uint32_t h = (ii & 1) ? (d >> 16) : (d & 0xffffu);
        s2[rt] = h | (h << 16);
      }

#pragma unroll
      for (int kh = 0; kh < 2; ++kh) {
        // 4 coalesced B-fragment loads (16B/lane from a 1KB-contig region)
        short8 wf[4];
#pragma unroll
        for (int ct = 0; ct < 4; ++ct)
          wf[ct] = __builtin_bit_cast(short8,
                     *(const uint4*)(pw + kh * 8192 + ct * 1024));
        // A fragments for this kh
        uint4 afr[4];
#pragma unroll
        for (int rt = 0; rt < 4; ++rt) {
          afr[rt].x = pkmul(s2[rt], b2c[rt][kh].x);
          afr[rt].y = pkmul(s2[rt], b2c[rt][kh].y);
          afr[rt].z = pkmul(s2[rt], b2c[rt][kh].z);
          afr[rt].w = pkmul(s2[rt], b2c[rt][kh].w);
        }
#pragma unroll
        for (int rt = 0; rt < 4; ++rt) {
          short8 af = __builtin_bit_cast(short8, afr[rt]);
#pragma unroll
          for (int ct = 0; ct < 4; ++ct)
            acc[rt][ct] = __builtin_amdgcn_mfma_f32_16x16x32_bf16(
                              af, wf[ct], acc[rt][ct], 0, 0, 0);
        }
      }
    }
  }

  // Epilogue. D: col(c)=l15, row(n)=quad*4+r within each 16x16 tile.
  if (P) {
    float* Pb = P + (size_t)blockIdx.x * OUT_ELEMS;   // slice = blockIdx.x
#pragma unroll
    for (int rt = 0; rt < 4; ++rt)
#pragma unroll
      for (int ct = 0; ct < 4; ++ct) {
        const int c = chalf * 64 + ct * 16 + l15;
        if (c < NCLS) {
#pragma unroll
          for (int r = 0; r < 4; ++r) {
            const int row = bm * 128 + mhalf * 64 + rt * 16 + quad * 4 + r;
            Pb[(size_t)row * NCLS + c] = acc[rt][ct][r];
          }
        }
      }
  } else {
#pragma unroll
    for (int rt = 0; rt < 4; ++rt)
#pragma unroll
      for (int ct = 0; ct < 4; ++ct) {
        const int c = chalf * 64 + ct * 16 + l15;
        if (c < NCLS) {
          const float bv = biasg[c];
#pragma unroll
          for (int r = 0; r < 4; ++r) {
            const int row = bm * 128 + mhalf * 64 + rt * 16 + quad * 4 + r;
            outd[(size_t)row * NCLS + c] = acc[rt][ct][r] + bv;
          }
        }
      }
  }
}

// Sum KS partial slices + f32 bias -> f32 output. float4-vectorized.
__global__ void reduce_bias(const float* __restrict__ P,
                            const float* __restrict__ biasg,
                            float* __restrict__ out, int KS)
{
  int i = blockIdx.x * blockDim.x + threadIdx.x;
  const int n4 = OUT_ELEMS / 4;           // 99328
  if (i >= n4) return;
  int c0 = (i * 4) % NCLS;
  int c1 = c0 + 1 == NCLS ? 0 : c0 + 1;
  int c2 = c1 + 1 == NCLS ? 0 : c1 + 1;
  int c3 = c2 + 1 == NCLS ? 0 : c2 + 1;
  float4 s;
  s.x = biasg[c0]; s.y = biasg[c1]; s.z = biasg[c2]; s.w = biasg[c3];
  const float4* P4 = (const float4*)P;
  for (int t = 0; t < KS; ++t) {
    float4 v = P4[(size_t)t * n4 + i];
    s.x += v.x; s.y += v.y; s.z += v.z; s.w += v.w;
  }
  ((float4*)out)[i] = s;
}

extern "C" void kernel_launch(void* const* d_in, const int* in_sizes, int n_in,
                              void* d_out, int out_size, void* d_ws, size_t ws_size,
                              hipStream_t stream) {
  const float* b1f = (const float*)d_in[0];   // [4096,768] f32
  const float* b2f = (const float*)d_in[1];   // [4096,768] f32
  const float* Wf  = (const float*)d_in[2];   // [97, 49152] f32
  const float* bbf = (const float*)d_in[3];   // [97] f32
  float* out = (float*)d_out;

  const size_t resv_full = WT_BYTES + 2 * EB_BYTES;   // 25,165,824
  const size_t slice     = (size_t)OUT_ELEMS * 4;     // 1,589,248
  static const int cands[] = {16, 12, 8, 6, 4, 3, 2, 1};  // klen mult of 512

  // Workspace plan: [Wt | b1b | b2b | P] (full) or [Wt | P] (b from f32).
  int KS = 0; bool bmir = false;
  for (int i = 0; i < 8; ++i)
    if (resv_full + (size_t)cands[i] * slice <= ws_size) { KS = cands[i]; bmir = true; break; }
  if (!bmir)
    for (int i = 0; i < 8; ++i)
      if (WT_BYTES + (size_t)cands[i] * slice <= ws_size) { KS = cands[i]; break; }

  uint4* Wt  = (uint4*)d_ws;
  uint4* b1b = (uint4*)((char*)d_ws + WT_BYTES);
  uint4* b2b = (uint4*)((char*)d_ws + WT_BYTES + EB_BYTES);
  const int nwt = NK32 * 128 * 4;
  const int nE8 = E_ELEMS / 8;
  const int nprep = bmir ? (nwt + 2 * nE8) : nwt;

  prep<<<(nprep + 255) / 256, 256, 0, stream>>>(Wf, b1f, b2f, Wt, b1b, b2b, nprep);

  if (KS > 0) {
    float* P = (float*)((char*)d_ws + (bmir ? resv_full : WT_BYTES));
    if (bmir)
      bilinear_main<true><<<dim3(KS, 32), 256, 0, stream>>>(
          (const void*)b1b, (const void*)b2b, (const char*)Wt, bbf, P, nullptr, KTOT / KS);
    else
      bilinear_main<false><<<dim3(KS, 32), 256, 0, stream>>>(
          (const void*)b1f, (const void*)b2f, (const char*)Wt, bbf, P, nullptr, KTOT / KS);
    reduce_bias<<<(OUT_ELEMS / 4 + 255) / 256, 256, 0, stream>>>(P, bbf, out, KS);
  } else {
    // Minimal-workspace fallback: single slice, direct f32 output.
    bilinear_main<false><<<dim3(1, 32), 256, 0, stream>>>(
        (const void*)b1f, (const void*)b2f, (const char*)Wt, bbf, nullptr, out, KTOT);
  }
}